// Round 4
// baseline (510.998 us; speedup 1.0000x reference)
//
#include <hip/hip_runtime.h>

// ---------------------------------------------------------------------------
// GQA block: out = Attn(x@Wq^T, x@Wk^T, x@Wv^T; sliding-window+sink) @ Wo^T
// B=2 T=2048 C=2048, NH=16 NKV=4 HS=128, WINDOW=1024 SINK=4.
// R4: K/V pre-packed into MFMA B-operand fragment order so all attention
// global loads are lane-contiguous (8 lines/instr instead of 64 -> kills the
// TA-transaction bottleneck seen in R3). Barrier-free softmax (no online max,
// scores bounded; l via ones-column MFMA) kept from R3.
// ---------------------------------------------------------------------------

#define T_SEQ 2048
#define NKV   4
#define HS    128
#define CDIM  2048
#define QKVN  3072
#define WIN   1024
#define SINKN 4
#define PSTR  68   // P LDS row stride (elems); 64 cols + 4 pad

typedef __bf16 bf16x8 __attribute__((ext_vector_type(8)));
typedef float  f32x4  __attribute__((ext_vector_type(4)));

#define MFMA16(A, B, C) __builtin_amdgcn_mfma_f32_16x16x32_bf16(A, B, C, 0, 0, 0)
#define EXP2(x) __builtin_amdgcn_exp2f(x)

__device__ inline unsigned short f2bu(float f) {  // fp32 -> bf16 bits, RNE
  unsigned int u = __float_as_uint(f);
  u += 0x7fffu + ((u >> 16) & 1u);
  return (unsigned short)(u >> 16);
}
__device__ inline __bf16 us2b(unsigned short u) {
  union { unsigned short u; __bf16 b; } t; t.u = u; return t.b;
}
__device__ inline f32x4 fzero4() { f32x4 z = {0.f, 0.f, 0.f, 0.f}; return z; }

// async global->LDS, 16B/lane. LDS dest is wave-uniform base + lane*16 (m104).
__device__ __forceinline__ void glds16(const void* g, const void* lds_uniform) {
  typedef __attribute__((address_space(1))) void gv;
  typedef __attribute__((address_space(3))) void lv;
  __builtin_amdgcn_global_load_lds((gv*)(unsigned long long)g,
                                   (lv*)(unsigned int)(unsigned long long)lds_uniform,
                                   16, 0, 0);
}

// ---------------- fp32 -> bf16 conversion (with optional scale) -------------
__global__ __launch_bounds__(256) void f2b_kernel(const float* __restrict__ in,
                                                  unsigned short* __restrict__ out,
                                                  int n, float scale) {
  int i = (blockIdx.x * 256 + threadIdx.x) * 4;
  if (i >= n) return;
  float4 v = *reinterpret_cast<const float4*>(in + i);
  ushort4 o;
  o.x = f2bu(v.x * scale); o.y = f2bu(v.y * scale);
  o.z = f2bu(v.z * scale); o.w = f2bu(v.w * scale);
  *reinterpret_cast<ushort4*>(out + i) = o;
}

// ---------------- C = A (M,K) @ B^T (N,K), m97 structure --------------------
__device__ inline void storeC(unsigned short* p, float v) { *p = f2bu(v); }
__device__ inline void storeC(float* p, float v) { *p = v; }

template <typename OutT>
__global__ __launch_bounds__(256) void gemm_abt(const unsigned short* __restrict__ A,
                                                const unsigned short* __restrict__ B,
                                                OutT* __restrict__ C,
                                                int M, int N, int K) {
  __shared__ __align__(16) unsigned short As[128 * 32];
  __shared__ __align__(16) unsigned short Bs[128 * 32];
  const int tid  = threadIdx.x;
  const int wave = tid >> 6, lane = tid & 63;
  const int quad = lane >> 4, l16 = lane & 15;
  const int wm = (wave >> 1) * 64, wn = (wave & 1) * 64;
  const int tm = blockIdx.x * 128, tn = blockIdx.y * 128;

  f32x4 acc[4][4];
#pragma unroll
  for (int i = 0; i < 4; ++i)
#pragma unroll
    for (int j = 0; j < 4; ++j) acc[i][j] = fzero4();

  for (int k0 = 0; k0 < K; k0 += 32) {
    __syncthreads();
#pragma unroll
    for (int it = 0; it < 2; ++it) {
      int chunk = wave * 2 + it;             // 0..7, wave-uniform
      int f = (chunk * 64 + lane) * 8;       // elem idx in 128x32 tile
      int r = f >> 5, c = f & 31;
      glds16(&A[(size_t)(tm + r) * K + k0 + c], &As[chunk * 512]);
      glds16(&B[(size_t)(tn + r) * K + k0 + c], &Bs[chunk * 512]);
    }
    __syncthreads();
    bf16x8 af[4], bfr[4];
#pragma unroll
    for (int i = 0; i < 4; ++i) {
      af[i]  = *reinterpret_cast<const bf16x8*>(&As[(wm + i * 16 + l16) * 32 + quad * 8]);
      bfr[i] = *reinterpret_cast<const bf16x8*>(&Bs[(wn + i * 16 + l16) * 32 + quad * 8]);
    }
#pragma unroll
    for (int i = 0; i < 4; ++i)
#pragma unroll
      for (int j = 0; j < 4; ++j) acc[i][j] = MFMA16(af[i], bfr[j], acc[i][j]);
  }
#pragma unroll
  for (int i = 0; i < 4; ++i)
#pragma unroll
    for (int j = 0; j < 4; ++j)
#pragma unroll
      for (int r = 0; r < 4; ++r) {
        int row = tm + wm + i * 16 + quad * 4 + r;
        int col = tn + wn + j * 16 + l16;
        storeC(&C[(size_t)row * N + col], acc[i][j][r]);
      }
}

// ---------------- K/V fragment packing --------------------------------------
// Kp: per (bk, kt64) an 8192-elem block; tile (c,nt) holds lane-linear
//     B-fragments: elem(lane=quad*16+l16, j) = K[key=kt+l16*4+nt][c*32+quad*8+j]
// Vp: per (bk, kt32) a 4096-elem block; tile dt: elem(lane,j) =
//     V[key=kt+quad*8+j][dim=dt*16+l16]
__global__ __launch_bounds__(256) void kvpack(const unsigned short* __restrict__ QKV,
                                              unsigned short* __restrict__ Kp,
                                              unsigned short* __restrict__ Vp) {
  const int tid  = threadIdx.x;
  const int kt64 = blockIdx.x;           // 0..31
  const int bk   = blockIdx.y;           // b*4 + kvh
  const int b = bk >> 2, kvh = bk & 3;
  const int kt = kt64 * 64;
  const int bT = b * T_SEQ;
  const int dq = tid & 15;               // dim octet: dims dq*8..dq*8+7

  unsigned short* kdst = &Kp[(size_t)(bk * 32 + kt64) * 8192];
#pragma unroll
  for (int it = 0; it < 4; ++it) {
    int key = it * 16 + (tid >> 4);
    float4 v = *reinterpret_cast<const float4*>(
        &QKV[(size_t)(bT + kt + key) * QKVN + 2048 + kvh * HS + dq * 8]);
    int c = dq >> 2, quad = dq & 3, nt = key & 3, l16s = key >> 2;
    *reinterpret_cast<float4*>(
        &kdst[((size_t)((c * 4 + nt) * 64 + quad * 16 + l16s)) * 8]) = v;
  }

#pragma unroll
  for (int it = 0; it < 4; ++it) {
    int key = it * 16 + (tid >> 4);
    float4 v = *reinterpret_cast<const float4*>(
        &QKV[(size_t)(bT + kt + key) * QKVN + 2560 + kvh * HS + dq * 8]);
    const unsigned short* pv = reinterpret_cast<const unsigned short*>(&v);
    int kt32 = kt64 * 2 + (key >> 5);
    int quad = (key & 31) >> 3, j = key & 7;
    unsigned short* vdst = &Vp[(size_t)(bk * 64 + kt32) * 4096];
#pragma unroll
    for (int j2 = 0; j2 < 8; ++j2) {
      int d = dq * 8 + j2, dt = d >> 4, l16v = d & 15;
      vdst[((size_t)(dt * 64 + quad * 16 + l16v)) * 8 + j] = pv[j2];
    }
  }
}

// ---------------- barrier-free flash attention ------------------------------
// grid (T/32, NKV, B); block 256 = 4 independent waves (wave = head in group).
// All K/V fragment loads fully coalesced from packed buffers. P via per-wave
// LDS slice; row-sum l via ones-column MFMA; no shuffles, no syncthreads.
__global__ __launch_bounds__(256, 2) void attn_kernel(const unsigned short* __restrict__ QKV,
                                                      const unsigned short* __restrict__ Kp,
                                                      const unsigned short* __restrict__ Vp,
                                                      unsigned short* __restrict__ Y) {
  __shared__ __align__(16) unsigned short Ps[4 * 32 * PSTR];
  const int tid  = threadIdx.x;
  const int wave = tid >> 6, lane = tid & 63;
  const int quad = lane >> 4, l16 = lane & 15;
  const int qt0 = (int)(gridDim.x - 1 - blockIdx.x) * 32;  // long blocks first
  const int kvh = blockIdx.y, b = blockIdx.z;
  const int bk = b * NKV + kvh;
  const int h  = kvh * 4 + wave;
  const int bT = b * T_SEQ;
  unsigned short* Pw = &Ps[wave * 32 * PSTR];

  // Q fragments (A-operand: m=l16, k=quad*8+j); Q pre-scaled by log2e/sqrt(HS)
  bf16x8 qa[2][4];
#pragma unroll
  for (int mt = 0; mt < 2; ++mt)
#pragma unroll
    for (int c = 0; c < 4; ++c)
      qa[mt][c] = *reinterpret_cast<const bf16x8*>(
          &QKV[(size_t)(bT + qt0 + mt * 16 + l16) * QKVN + h * HS + c * 32 + quad * 8]);

  bf16x8 ones;
#pragma unroll
  for (int j = 0; j < 8; ++j) ones[j] = us2b(0x3F80);  // bf16 1.0

  f32x4 o[2][9];   // [mt][dt]; dt=8 accumulates row-sum l
#pragma unroll
  for (int mt = 0; mt < 2; ++mt)
#pragma unroll
    for (int dt = 0; dt < 9; ++dt) o[mt][dt] = fzero4();

  const int start = (qt0 >= 1024) ? ((qt0 - 1023) & ~63) : 0;
  const int sink  = (start > 0) ? 1 : 0;
  const int nch   = ((qt0 + 32 - start + 63) >> 6) + sink;

  for (int ci = 0; ci < nch; ++ci) {
    const bool is_sink = (sink && ci == 0);
    const int  kt  = is_sink ? 0 : start + (ci - sink) * 64;
    const int  rem = qt0 + 32 - kt;
    const int  kcmax = is_sink ? 1 : (rem >= 64 ? 2 : ((rem + 31) >> 5));
    const bool full  = !is_sink && (kt + 63 <= qt0) && (kt >= qt0 - 992);

    f32x4 s[2][4];
#pragma unroll
    for (int nt = 0; nt < 4; ++nt) { s[0][nt] = fzero4(); s[1][nt] = fzero4(); }

    if (is_sink) {
      // direct (uncoalesced) K loads; once per wave, 16 rows only
#pragma unroll
      for (int c = 0; c < 4; ++c) {
        bf16x8 kf = *reinterpret_cast<const bf16x8*>(
            &QKV[(size_t)(bT + l16) * QKVN + 2048 + kvh * HS + c * 32 + quad * 8]);
        s[0][0] = MFMA16(qa[0][c], kf, s[0][0]);
        s[1][0] = MFMA16(qa[1][c], kf, s[1][0]);
      }
#pragma unroll
      for (int mt = 0; mt < 2; ++mt)
#pragma unroll
        for (int r = 0; r < 4; ++r) {
          const int row = mt * 16 + quad * 4 + r;
          Pw[row * PSTR + l16]      = (l16 < SINKN) ? f2bu(EXP2(s[mt][0][r])) : 0;
          Pw[row * PSTR + 16 + l16] = 0;
        }
    } else {
      const unsigned short* kb = &Kp[(size_t)(bk * 32 + (kt >> 6)) * 8192 + lane * 8];
      const unsigned short* vb = &Vp[(size_t)(bk * 64 + (kt >> 5)) * 4096 + lane * 8];

      // hoist V fragment loads (independent of QK/P) for latency overlap
      bf16x8 vf[2][8];
#pragma unroll
      for (int kc = 0; kc < 2; ++kc)
        if (kc < kcmax)
#pragma unroll
          for (int dt = 0; dt < 8; ++dt)
            vf[kc][dt] = *reinterpret_cast<const bf16x8*>(&vb[(kc * 8 + dt) * 512]);

#pragma unroll
      for (int c = 0; c < 4; ++c) {
        bf16x8 kf[4];
#pragma unroll
        for (int nt = 0; nt < 4; ++nt)
          kf[nt] = *reinterpret_cast<const bf16x8*>(&kb[(c * 4 + nt) * 512]);
#pragma unroll
        for (int nt = 0; nt < 4; ++nt) {
          s[0][nt] = MFMA16(qa[0][c], kf[nt], s[0][nt]);
          s[1][nt] = MFMA16(qa[1][c], kf[nt], s[1][nt]);
        }
      }

      if (full) {
#pragma unroll
        for (int mt = 0; mt < 2; ++mt)
#pragma unroll
          for (int r = 0; r < 4; ++r) {
            const int row = mt * 16 + quad * 4 + r;
            ushort4 pk;
            pk.x = f2bu(EXP2(s[mt][0][r]));
            pk.y = f2bu(EXP2(s[mt][1][r]));
            pk.z = f2bu(EXP2(s[mt][2][r]));
            pk.w = f2bu(EXP2(s[mt][3][r]));
            *reinterpret_cast<ushort4*>(&Pw[row * PSTR + l16 * 4]) = pk;
          }
      } else {
#pragma unroll
        for (int mt = 0; mt < 2; ++mt)
#pragma unroll
          for (int r = 0; r < 4; ++r) {
            const int row = mt * 16 + quad * 4 + r;
            const int qi  = qt0 + row;
            float p[4];
#pragma unroll
            for (int nt = 0; nt < 4; ++nt) {
              int kj = kt + l16 * 4 + nt;
              bool ok = ((kj <= qi) && (kj + (WIN - 1) >= qi)) ||
                        ((kj < SINKN) && (qi >= SINKN));
              p[nt] = ok ? EXP2(s[mt][nt][r]) : 0.f;
            }
            ushort4 pk;
            pk.x = f2bu(p[0]); pk.y = f2bu(p[1]);
            pk.z = f2bu(p[2]); pk.w = f2bu(p[3]);
            *reinterpret_cast<ushort4*>(&Pw[row * PSTR + l16 * 4]) = pk;
          }
      }
      asm volatile("s_waitcnt lgkmcnt(0)" ::: "memory");  // wave-local P drain

#pragma unroll
      for (int kc = 0; kc < 2; ++kc)
        if (kc < kcmax) {
#pragma unroll
          for (int mt = 0; mt < 2; ++mt) {
            bf16x8 pf = *reinterpret_cast<const bf16x8*>(
                &Pw[(mt * 16 + l16) * PSTR + kc * 32 + quad * 8]);
#pragma unroll
            for (int dt = 0; dt < 8; ++dt)
              o[mt][dt] = MFMA16(pf, vf[kc][dt], o[mt][dt]);
            o[mt][8] = MFMA16(pf, ones, o[mt][8]);
          }
        }
      continue;
    }

    // ---- sink-chunk PV (standard col map, keys 0..31, direct V loads) ----
    asm volatile("s_waitcnt lgkmcnt(0)" ::: "memory");
    {
      const unsigned short* vb = &Vp[(size_t)(bk * 64) * 4096 + lane * 8];
      bf16x8 vf[8];
#pragma unroll
      for (int dt = 0; dt < 8; ++dt)
        vf[dt] = *reinterpret_cast<const bf16x8*>(&vb[dt * 512]);
      // note: Vp tile key order is key=quad*8+j (standard), matching P cols
#pragma unroll
      for (int mt = 0; mt < 2; ++mt) {
        bf16x8 pf = *reinterpret_cast<const bf16x8*>(
            &Pw[(mt * 16 + l16) * PSTR + quad * 8]);
#pragma unroll
        for (int dt = 0; dt < 8; ++dt) o[mt][dt] = MFMA16(pf, vf[dt], o[mt][dt]);
        o[mt][8] = MFMA16(pf, ones, o[mt][8]);
      }
    }
  }

  // ---- normalize by l and store ----
#pragma unroll
  for (int mt = 0; mt < 2; ++mt) {
    float inv[4];
#pragma unroll
    for (int r = 0; r < 4; ++r) inv[r] = __builtin_amdgcn_rcpf(o[mt][8][r]);
#pragma unroll
    for (int dt = 0; dt < 8; ++dt)
#pragma unroll
      for (int r = 0; r < 4; ++r)
        Y[(size_t)(bT + qt0 + mt * 16 + quad * 4 + r) * CDIM + h * HS + dt * 16 + l16] =
            f2bu(o[mt][dt][r] * inv[r]);
  }
}

// ---------------------------------------------------------------------------
extern "C" void kernel_launch(void* const* d_in, const int* in_sizes, int n_in,
                              void* d_out, int out_size, void* d_ws, size_t ws_size,
                              hipStream_t stream) {
  const float* x  = (const float*)d_in[0];
  const float* Wq = (const float*)d_in[1];
  const float* Wk = (const float*)d_in[2];
  const float* Wv = (const float*)d_in[3];
  const float* Wo = (const float*)d_in[4];
  float* out = (float*)d_out;

  // workspace layout (bf16 elems); total 62.9 MB
  unsigned short* base = (unsigned short*)d_ws;
  unsigned short* xb   = base;              // x bf16 (8388608); later Y
  unsigned short* wqb  = xb   + 8388608;    // Wq bf16 (4194304); later Kp+Vp
  unsigned short* wkb  = wqb  + 4194304;    // Wk bf16 (1048576)  } contiguous
  unsigned short* wvb  = wkb  + 1048576;    // Wv bf16 (1048576)  } B for QKV
  unsigned short* wob  = wvb  + 1048576;    // Wo bf16 (4194304)
  unsigned short* QKVb = wob  + 4194304;    // QKV (4096 x 3072)
  unsigned short* Kpb  = wqb;               // packed K (2097152)
  unsigned short* Vpb  = wqb + 2097152;     // packed V (2097152)
  unsigned short* Yb   = xb;                // attn out (4096 x 2048)

  // 1/sqrt(HS) * log2(e) folded into Wq so exp2 is native
  const float qscale = 0.08838834764831845f * 1.4426950408889634f;
  f2b_kernel<<<8192, 256, 0, stream>>>(x,  xb,  8388608, 1.0f);
  f2b_kernel<<<4096, 256, 0, stream>>>(Wq, wqb, 4194304, qscale);
  f2b_kernel<<<1024, 256, 0, stream>>>(Wk, wkb, 1048576, 1.0f);
  f2b_kernel<<<1024, 256, 0, stream>>>(Wv, wvb, 1048576, 1.0f);
  f2b_kernel<<<4096, 256, 0, stream>>>(Wo, wob, 4194304, 1.0f);

  // fused QKV projection: B = [Wq; Wk; Wv], N = 3072
  gemm_abt<unsigned short><<<dim3(32, 24), 256, 0, stream>>>(xb, wqb, QKVb, 4096, QKVN, 2048);

  kvpack<<<dim3(32, 8), 256, 0, stream>>>(QKVb, Kpb, Vpb);

  attn_kernel<<<dim3(64, 4, 2), 256, 0, stream>>>(QKVb, Kpb, Vpb, Yb);

  gemm_abt<float><<<dim3(32, 16), 256, 0, stream>>>(Yb, wob, out, 4096, 2048, 2048);
}

// Round 5
// 391.441 us; speedup vs baseline: 1.3054x; 1.3054x over previous
//
#include <hip/hip_runtime.h>

// ---------------------------------------------------------------------------
// GQA block: out = Attn(x@Wq^T, x@Wk^T, x@Wv^T; sliding-window+sink) @ Wo^T
// B=2 T=2048 C=2048, NH=16 NKV=4 HS=128, WINDOW=1024 SINK=4.
// R5: R4's packed-fragment K/V loads WITHOUT the register-pressure bombs that
// caused scratch spills (552 MB writes): no V hoist, no VGPR cap. Barrier-free
// softmax (bounded scores, no online max; l via ones-column MFMA).
// ---------------------------------------------------------------------------

#define T_SEQ 2048
#define NKV   4
#define HS    128
#define CDIM  2048
#define QKVN  3072
#define WIN   1024
#define SINKN 4
#define PSTR  68   // P LDS row stride (elems); 64 cols + 4 pad

typedef __bf16 bf16x8 __attribute__((ext_vector_type(8)));
typedef float  f32x4  __attribute__((ext_vector_type(4)));

#define MFMA16(A, B, C) __builtin_amdgcn_mfma_f32_16x16x32_bf16(A, B, C, 0, 0, 0)
#define EXP2(x) __builtin_amdgcn_exp2f(x)

__device__ inline unsigned short f2bu(float f) {  // fp32 -> bf16 bits, RNE
  unsigned int u = __float_as_uint(f);
  u += 0x7fffu + ((u >> 16) & 1u);
  return (unsigned short)(u >> 16);
}
__device__ inline __bf16 us2b(unsigned short u) {
  union { unsigned short u; __bf16 b; } t; t.u = u; return t.b;
}
__device__ inline f32x4 fzero4() { f32x4 z = {0.f, 0.f, 0.f, 0.f}; return z; }

// async global->LDS, 16B/lane. LDS dest is wave-uniform base + lane*16 (m104).
__device__ __forceinline__ void glds16(const void* g, const void* lds_uniform) {
  typedef __attribute__((address_space(1))) void gv;
  typedef __attribute__((address_space(3))) void lv;
  __builtin_amdgcn_global_load_lds((gv*)(unsigned long long)g,
                                   (lv*)(unsigned int)(unsigned long long)lds_uniform,
                                   16, 0, 0);
}

// ---------------- fp32 -> bf16 conversion (with optional scale) -------------
__global__ __launch_bounds__(256) void f2b_kernel(const float* __restrict__ in,
                                                  unsigned short* __restrict__ out,
                                                  int n, float scale) {
  int i = (blockIdx.x * 256 + threadIdx.x) * 4;
  if (i >= n) return;
  float4 v = *reinterpret_cast<const float4*>(in + i);
  ushort4 o;
  o.x = f2bu(v.x * scale); o.y = f2bu(v.y * scale);
  o.z = f2bu(v.z * scale); o.w = f2bu(v.w * scale);
  *reinterpret_cast<ushort4*>(out + i) = o;
}

// ---------------- C = A (M,K) @ B^T (N,K), m97 structure --------------------
__device__ inline void storeC(unsigned short* p, float v) { *p = f2bu(v); }
__device__ inline void storeC(float* p, float v) { *p = v; }

template <typename OutT>
__global__ __launch_bounds__(256) void gemm_abt(const unsigned short* __restrict__ A,
                                                const unsigned short* __restrict__ B,
                                                OutT* __restrict__ C,
                                                int M, int N, int K) {
  __shared__ __align__(16) unsigned short As[128 * 32];
  __shared__ __align__(16) unsigned short Bs[128 * 32];
  const int tid  = threadIdx.x;
  const int wave = tid >> 6, lane = tid & 63;
  const int quad = lane >> 4, l16 = lane & 15;
  const int wm = (wave >> 1) * 64, wn = (wave & 1) * 64;
  const int tm = blockIdx.x * 128, tn = blockIdx.y * 128;

  f32x4 acc[4][4];
#pragma unroll
  for (int i = 0; i < 4; ++i)
#pragma unroll
    for (int j = 0; j < 4; ++j) acc[i][j] = fzero4();

  for (int k0 = 0; k0 < K; k0 += 32) {
    __syncthreads();
#pragma unroll
    for (int it = 0; it < 2; ++it) {
      int chunk = wave * 2 + it;             // 0..7, wave-uniform
      int f = (chunk * 64 + lane) * 8;       // elem idx in 128x32 tile
      int r = f >> 5, c = f & 31;
      glds16(&A[(size_t)(tm + r) * K + k0 + c], &As[chunk * 512]);
      glds16(&B[(size_t)(tn + r) * K + k0 + c], &Bs[chunk * 512]);
    }
    __syncthreads();
    bf16x8 af[4], bfr[4];
#pragma unroll
    for (int i = 0; i < 4; ++i) {
      af[i]  = *reinterpret_cast<const bf16x8*>(&As[(wm + i * 16 + l16) * 32 + quad * 8]);
      bfr[i] = *reinterpret_cast<const bf16x8*>(&Bs[(wn + i * 16 + l16) * 32 + quad * 8]);
    }
#pragma unroll
    for (int i = 0; i < 4; ++i)
#pragma unroll
      for (int j = 0; j < 4; ++j) acc[i][j] = MFMA16(af[i], bfr[j], acc[i][j]);
  }
#pragma unroll
  for (int i = 0; i < 4; ++i)
#pragma unroll
    for (int j = 0; j < 4; ++j)
#pragma unroll
      for (int r = 0; r < 4; ++r) {
        int row = tm + wm + i * 16 + quad * 4 + r;
        int col = tn + wn + j * 16 + l16;
        storeC(&C[(size_t)row * N + col], acc[i][j][r]);
      }
}

// ---------------- K/V fragment packing --------------------------------------
// Kp: per (bk, kt64) an 8192-elem block; tile (c,nt) holds lane-linear
//     B-fragments: elem(lane=quad*16+l16, j) = K[key=kt+l16*4+nt][c*32+quad*8+j]
// Vp: per (bk, kt32) a 4096-elem block; tile dt: elem(lane,j) =
//     V[key=kt+quad*8+j][dim=dt*16+l16]
__global__ __launch_bounds__(256) void kvpack(const unsigned short* __restrict__ QKV,
                                              unsigned short* __restrict__ Kp,
                                              unsigned short* __restrict__ Vp) {
  const int tid  = threadIdx.x;
  const int kt64 = blockIdx.x;           // 0..31
  const int bk   = blockIdx.y;           // b*4 + kvh
  const int b = bk >> 2, kvh = bk & 3;
  const int kt = kt64 * 64;
  const int bT = b * T_SEQ;
  const int dq = tid & 15;               // dim octet: dims dq*8..dq*8+7

  unsigned short* kdst = &Kp[(size_t)(bk * 32 + kt64) * 8192];
#pragma unroll
  for (int it = 0; it < 4; ++it) {
    int key = it * 16 + (tid >> 4);
    float4 v = *reinterpret_cast<const float4*>(
        &QKV[(size_t)(bT + kt + key) * QKVN + 2048 + kvh * HS + dq * 8]);
    int c = dq >> 2, quad = dq & 3, nt = key & 3, l16s = key >> 2;
    *reinterpret_cast<float4*>(
        &kdst[((size_t)((c * 4 + nt) * 64 + quad * 16 + l16s)) * 8]) = v;
  }

#pragma unroll
  for (int it = 0; it < 4; ++it) {
    int key = it * 16 + (tid >> 4);
    float4 v = *reinterpret_cast<const float4*>(
        &QKV[(size_t)(bT + kt + key) * QKVN + 2560 + kvh * HS + dq * 8]);
    const unsigned short* pv = reinterpret_cast<const unsigned short*>(&v);
    int kt32 = kt64 * 2 + (key >> 5);
    int quad = (key & 31) >> 3, j = key & 7;
    unsigned short* vdst = &Vp[(size_t)(bk * 64 + kt32) * 4096];
#pragma unroll
    for (int j2 = 0; j2 < 8; ++j2) {
      int d = dq * 8 + j2, dt = d >> 4, l16v = d & 15;
      vdst[((size_t)(dt * 64 + quad * 16 + l16v)) * 8 + j] = pv[j2];
    }
  }
}

// ---------------- barrier-free flash attention ------------------------------
// grid (T/32, NKV, B); block 256 = 4 independent waves (wave = head in group).
// All K/V fragment loads fully coalesced from packed buffers. P via per-wave
// LDS slice; row-sum l via ones-column MFMA; no shuffles, no syncthreads.
__global__ __launch_bounds__(256) void attn_kernel(const unsigned short* __restrict__ QKV,
                                                   const unsigned short* __restrict__ Kp,
                                                   const unsigned short* __restrict__ Vp,
                                                   unsigned short* __restrict__ Y) {
  __shared__ __align__(16) unsigned short Ps[4 * 32 * PSTR];
  const int tid  = threadIdx.x;
  const int wave = tid >> 6, lane = tid & 63;
  const int quad = lane >> 4, l16 = lane & 15;
  const int qt0 = (int)(gridDim.x - 1 - blockIdx.x) * 32;  // long blocks first
  const int kvh = blockIdx.y, b = blockIdx.z;
  const int bk = b * NKV + kvh;
  const int h  = kvh * 4 + wave;
  const int bT = b * T_SEQ;
  unsigned short* Pw = &Ps[wave * 32 * PSTR];

  // Q fragments (A-operand: m=l16, k=quad*8+j); Q pre-scaled by log2e/sqrt(HS)
  bf16x8 qa[2][4];
#pragma unroll
  for (int mt = 0; mt < 2; ++mt)
#pragma unroll
    for (int c = 0; c < 4; ++c)
      qa[mt][c] = *reinterpret_cast<const bf16x8*>(
          &QKV[(size_t)(bT + qt0 + mt * 16 + l16) * QKVN + h * HS + c * 32 + quad * 8]);

  bf16x8 ones;
#pragma unroll
  for (int j = 0; j < 8; ++j) ones[j] = us2b(0x3F80);  // bf16 1.0

  f32x4 o[2][9];   // [mt][dt]; dt=8 accumulates row-sum l
#pragma unroll
  for (int mt = 0; mt < 2; ++mt)
#pragma unroll
    for (int dt = 0; dt < 9; ++dt) o[mt][dt] = fzero4();

  const int start = (qt0 >= 1024) ? ((qt0 - 1023) & ~63) : 0;
  const int sink  = (start > 0) ? 1 : 0;
  const int nch   = ((qt0 + 32 - start + 63) >> 6) + sink;

  for (int ci = 0; ci < nch; ++ci) {
    const bool is_sink = (sink && ci == 0);
    const int  kt  = is_sink ? 0 : start + (ci - sink) * 64;
    const int  rem = qt0 + 32 - kt;
    const int  kcmax = is_sink ? 1 : (rem >= 64 ? 2 : ((rem + 31) >> 5));
    const bool full  = !is_sink && (kt + 63 <= qt0) && (kt >= qt0 - 992);

    f32x4 s[2][4];
#pragma unroll
    for (int nt = 0; nt < 4; ++nt) { s[0][nt] = fzero4(); s[1][nt] = fzero4(); }

    if (is_sink) {
      // direct (uncoalesced) K loads; once per wave, 16 rows only
#pragma unroll
      for (int c = 0; c < 4; ++c) {
        bf16x8 kf = *reinterpret_cast<const bf16x8*>(
            &QKV[(size_t)(bT + l16) * QKVN + 2048 + kvh * HS + c * 32 + quad * 8]);
        s[0][0] = MFMA16(qa[0][c], kf, s[0][0]);
        s[1][0] = MFMA16(qa[1][c], kf, s[1][0]);
      }
#pragma unroll
      for (int mt = 0; mt < 2; ++mt)
#pragma unroll
        for (int r = 0; r < 4; ++r) {
          const int row = mt * 16 + quad * 4 + r;
          Pw[row * PSTR + l16]      = (l16 < SINKN) ? f2bu(EXP2(s[mt][0][r])) : 0;
          Pw[row * PSTR + 16 + l16] = 0;
        }
      asm volatile("s_waitcnt lgkmcnt(0)" ::: "memory");
      // sink-chunk PV (standard col map, keys 0..31)
      const unsigned short* vb = &Vp[(size_t)(bk * 64) * 4096 + lane * 8];
#pragma unroll
      for (int mt = 0; mt < 2; ++mt) {
        bf16x8 pf = *reinterpret_cast<const bf16x8*>(
            &Pw[(mt * 16 + l16) * PSTR + quad * 8]);
#pragma unroll
        for (int dt = 0; dt < 8; ++dt) {
          bf16x8 vf = *reinterpret_cast<const bf16x8*>(&vb[dt * 512]);
          o[mt][dt] = MFMA16(pf, vf, o[mt][dt]);
        }
        o[mt][8] = MFMA16(pf, ones, o[mt][8]);
      }
      continue;
    }

    const unsigned short* kb = &Kp[(size_t)(bk * 32 + (kt >> 6)) * 8192 + lane * 8];
    const unsigned short* vb = &Vp[(size_t)(bk * 64 + (kt >> 5)) * 4096 + lane * 8];

#pragma unroll
    for (int c = 0; c < 4; ++c) {
      bf16x8 kf[4];
#pragma unroll
      for (int nt = 0; nt < 4; ++nt)
        kf[nt] = *reinterpret_cast<const bf16x8*>(&kb[(c * 4 + nt) * 512]);
#pragma unroll
      for (int nt = 0; nt < 4; ++nt) {
        s[0][nt] = MFMA16(qa[0][c], kf[nt], s[0][nt]);
        s[1][nt] = MFMA16(qa[1][c], kf[nt], s[1][nt]);
      }
    }

    if (full) {
#pragma unroll
      for (int mt = 0; mt < 2; ++mt)
#pragma unroll
        for (int r = 0; r < 4; ++r) {
          const int row = mt * 16 + quad * 4 + r;
          ushort4 pk;
          pk.x = f2bu(EXP2(s[mt][0][r]));
          pk.y = f2bu(EXP2(s[mt][1][r]));
          pk.z = f2bu(EXP2(s[mt][2][r]));
          pk.w = f2bu(EXP2(s[mt][3][r]));
          *reinterpret_cast<ushort4*>(&Pw[row * PSTR + l16 * 4]) = pk;
        }
    } else {
#pragma unroll
      for (int mt = 0; mt < 2; ++mt)
#pragma unroll
        for (int r = 0; r < 4; ++r) {
          const int row = mt * 16 + quad * 4 + r;
          const int qi  = qt0 + row;
          float p[4];
#pragma unroll
          for (int nt = 0; nt < 4; ++nt) {
            int kj = kt + l16 * 4 + nt;
            bool ok = ((kj <= qi) && (kj + (WIN - 1) >= qi)) ||
                      ((kj < SINKN) && (qi >= SINKN));
            p[nt] = ok ? EXP2(s[mt][nt][r]) : 0.f;
          }
          ushort4 pk;
          pk.x = f2bu(p[0]); pk.y = f2bu(p[1]);
          pk.z = f2bu(p[2]); pk.w = f2bu(p[3]);
          *reinterpret_cast<ushort4*>(&Pw[row * PSTR + l16 * 4]) = pk;
        }
    }
    asm volatile("s_waitcnt lgkmcnt(0)" ::: "memory");  // wave-local P drain

#pragma unroll
    for (int kc = 0; kc < 2; ++kc)
      if (kc < kcmax) {
#pragma unroll
        for (int mt = 0; mt < 2; ++mt) {
          bf16x8 pf = *reinterpret_cast<const bf16x8*>(
              &Pw[(mt * 16 + l16) * PSTR + kc * 32 + quad * 8]);
#pragma unroll
          for (int dt = 0; dt < 8; ++dt) {
            bf16x8 vf = *reinterpret_cast<const bf16x8*>(&vb[(kc * 8 + dt) * 512]);
            o[mt][dt] = MFMA16(pf, vf, o[mt][dt]);
          }
          o[mt][8] = MFMA16(pf, ones, o[mt][8]);
        }
      }
  }

  // ---- normalize by l and store ----
#pragma unroll
  for (int mt = 0; mt < 2; ++mt) {
    float inv[4];
#pragma unroll
    for (int r = 0; r < 4; ++r) inv[r] = __builtin_amdgcn_rcpf(o[mt][8][r]);
#pragma unroll
    for (int dt = 0; dt < 8; ++dt)
#pragma unroll
      for (int r = 0; r < 4; ++r)
        Y[(size_t)(bT + qt0 + mt * 16 + quad * 4 + r) * CDIM + h * HS + dt * 16 + l16] =
            f2bu(o[mt][dt][r] * inv[r]);
  }
}

// ---------------------------------------------------------------------------
extern "C" void kernel_launch(void* const* d_in, const int* in_sizes, int n_in,
                              void* d_out, int out_size, void* d_ws, size_t ws_size,
                              hipStream_t stream) {
  const float* x  = (const float*)d_in[0];
  const float* Wq = (const float*)d_in[1];
  const float* Wk = (const float*)d_in[2];
  const float* Wv = (const float*)d_in[3];
  const float* Wo = (const float*)d_in[4];
  float* out = (float*)d_out;

  // workspace layout (bf16 elems); total 62.9 MB
  unsigned short* base = (unsigned short*)d_ws;
  unsigned short* xb   = base;              // x bf16 (8388608); later Y
  unsigned short* wqb  = xb   + 8388608;    // Wq bf16 (4194304); later Kp+Vp
  unsigned short* wkb  = wqb  + 4194304;    // Wk bf16 (1048576)  } contiguous
  unsigned short* wvb  = wkb  + 1048576;    // Wv bf16 (1048576)  } B for QKV
  unsigned short* wob  = wvb  + 1048576;    // Wo bf16 (4194304)
  unsigned short* QKVb = wob  + 4194304;    // QKV (4096 x 3072)
  unsigned short* Kpb  = wqb;               // packed K (2097152)
  unsigned short* Vpb  = wqb + 2097152;     // packed V (2097152)
  unsigned short* Yb   = xb;                // attn out (4096 x 2048)

  // 1/sqrt(HS) * log2(e) folded into Wq so exp2 is native
  const float qscale = 0.08838834764831845f * 1.4426950408889634f;
  f2b_kernel<<<8192, 256, 0, stream>>>(x,  xb,  8388608, 1.0f);
  f2b_kernel<<<4096, 256, 0, stream>>>(Wq, wqb, 4194304, qscale);
  f2b_kernel<<<1024, 256, 0, stream>>>(Wk, wkb, 1048576, 1.0f);
  f2b_kernel<<<1024, 256, 0, stream>>>(Wv, wvb, 1048576, 1.0f);
  f2b_kernel<<<4096, 256, 0, stream>>>(Wo, wob, 4194304, 1.0f);

  // fused QKV projection: B = [Wq; Wk; Wv], N = 3072
  gemm_abt<unsigned short><<<dim3(32, 24), 256, 0, stream>>>(xb, wqb, QKVb, 4096, QKVN, 2048);

  kvpack<<<dim3(32, 8), 256, 0, stream>>>(QKVb, Kpb, Vpb);

  attn_kernel<<<dim3(64, 4, 2), 256, 0, stream>>>(QKVb, Kpb, Vpb, Yb);

  gemm_abt<float><<<dim3(32, 16), 256, 0, stream>>>(Yb, wob, out, 4096, 2048, 2048);
}

// Round 6
// 373.927 us; speedup vs baseline: 1.3666x; 1.0468x over previous
//
#include <hip/hip_runtime.h>

// ---------------------------------------------------------------------------
// GQA block: out = Attn(x@Wq^T, x@Wk^T, x@Wv^T; sliding-window+sink) @ Wo^T
// B=2 T=2048 C=2048, NH=16 NKV=4 HS=128, WINDOW=1024 SINK=4.
// R6: attention parallelism fix. Since softmax runs without online max
// (bounded scores), O and l are LINEAR in key chunks -> split the key range
// across the block's 4 waves (block = 32 queries x ONE head) and tree-reduce
// via LDS at the end. 2048 uniform blocks vs 512 skewed ones. Also: fused
// fp32->bf16 conversion (1 launch), trunc bf16 for P, coalesced Y store.
// ---------------------------------------------------------------------------

#define T_SEQ 2048
#define NKV   4
#define HS    128
#define CDIM  2048
#define QKVN  3072
#define WIN   1024
#define SINKN 4
#define PSTR  68        // P LDS row stride (elems)
#define RSTR  76        // reduction lane stride (floats, 19 quads -> ~2-way)

typedef __bf16 bf16x8 __attribute__((ext_vector_type(8)));
typedef float  f32x4  __attribute__((ext_vector_type(4)));

#define MFMA16(A, B, C) __builtin_amdgcn_mfma_f32_16x16x32_bf16(A, B, C, 0, 0, 0)
#define EXP2(x) __builtin_amdgcn_exp2f(x)

__device__ inline unsigned short f2bu(float f) {  // fp32 -> bf16 bits, RNE
  unsigned int u = __float_as_uint(f);
  u += 0x7fffu + ((u >> 16) & 1u);
  return (unsigned short)(u >> 16);
}
// pack hi16(u0), hi16(u1) -> one u32 (bf16 truncation; bias cancels in O/l)
__device__ inline unsigned int pkhi(float f0, float f1) {
  return __builtin_amdgcn_perm(__float_as_uint(f1), __float_as_uint(f0),
                               0x07060302u);
}
__device__ inline __bf16 us2b(unsigned short u) {
  union { unsigned short u; __bf16 b; } t; t.u = u; return t.b;
}
__device__ inline f32x4 fzero4() { f32x4 z = {0.f, 0.f, 0.f, 0.f}; return z; }

// async global->LDS, 16B/lane. LDS dest is wave-uniform base + lane*16 (m104).
__device__ __forceinline__ void glds16(const void* g, const void* lds_uniform) {
  typedef __attribute__((address_space(1))) void gv;
  typedef __attribute__((address_space(3))) void lv;
  __builtin_amdgcn_global_load_lds((gv*)(unsigned long long)g,
                                   (lv*)(unsigned int)(unsigned long long)lds_uniform,
                                   16, 0, 0);
}

// ---------------- fused fp32 -> bf16 conversion (all 5 inputs) --------------
// dest ws ranges are contiguous: [x | Wq | Wk | Wv | Wo]; Wq gets qscale.
#define SZ_X  8388608
#define SZ_WQ 4194304
#define SZ_WK 1048576
#define OFF_WQ (SZ_X)
#define OFF_WK (SZ_X + SZ_WQ)
#define OFF_WV (OFF_WK + SZ_WK)
#define OFF_WO (OFF_WV + SZ_WK)
#define SZ_ALL (OFF_WO + SZ_WQ)

__global__ __launch_bounds__(256) void f2b_all(const float* __restrict__ x,
                                               const float* __restrict__ wq,
                                               const float* __restrict__ wk,
                                               const float* __restrict__ wv,
                                               const float* __restrict__ wo,
                                               unsigned short* __restrict__ out,
                                               float qs) {
  int i = (blockIdx.x * 256 + threadIdx.x) * 4;
  const float* src; int off; float sc = 1.0f;
  if (i < OFF_WQ)      { src = x;  off = 0; }
  else if (i < OFF_WK) { src = wq; off = OFF_WQ; sc = qs; }
  else if (i < OFF_WV) { src = wk; off = OFF_WK; }
  else if (i < OFF_WO) { src = wv; off = OFF_WV; }
  else                 { src = wo; off = OFF_WO; }
  float4 v = *reinterpret_cast<const float4*>(src + (i - off));
  ushort4 o;
  o.x = f2bu(v.x * sc); o.y = f2bu(v.y * sc);
  o.z = f2bu(v.z * sc); o.w = f2bu(v.w * sc);
  *reinterpret_cast<ushort4*>(out + i) = o;
}

// ---------------- C = A (M,K) @ B^T (N,K), m97 structure --------------------
__device__ inline void storeC(unsigned short* p, float v) { *p = f2bu(v); }
__device__ inline void storeC(float* p, float v) { *p = v; }

template <typename OutT>
__global__ __launch_bounds__(256) void gemm_abt(const unsigned short* __restrict__ A,
                                                const unsigned short* __restrict__ B,
                                                OutT* __restrict__ C,
                                                int M, int N, int K) {
  __shared__ __align__(16) unsigned short As[128 * 32];
  __shared__ __align__(16) unsigned short Bs[128 * 32];
  const int tid  = threadIdx.x;
  const int wave = tid >> 6, lane = tid & 63;
  const int quad = lane >> 4, l16 = lane & 15;
  const int wm = (wave >> 1) * 64, wn = (wave & 1) * 64;
  const int tm = blockIdx.x * 128, tn = blockIdx.y * 128;

  f32x4 acc[4][4];
#pragma unroll
  for (int i = 0; i < 4; ++i)
#pragma unroll
    for (int j = 0; j < 4; ++j) acc[i][j] = fzero4();

  for (int k0 = 0; k0 < K; k0 += 32) {
    __syncthreads();
#pragma unroll
    for (int it = 0; it < 2; ++it) {
      int chunk = wave * 2 + it;             // 0..7, wave-uniform
      int f = (chunk * 64 + lane) * 8;       // elem idx in 128x32 tile
      int r = f >> 5, c = f & 31;
      glds16(&A[(size_t)(tm + r) * K + k0 + c], &As[chunk * 512]);
      glds16(&B[(size_t)(tn + r) * K + k0 + c], &Bs[chunk * 512]);
    }
    __syncthreads();
    bf16x8 af[4], bfr[4];
#pragma unroll
    for (int i = 0; i < 4; ++i) {
      af[i]  = *reinterpret_cast<const bf16x8*>(&As[(wm + i * 16 + l16) * 32 + quad * 8]);
      bfr[i] = *reinterpret_cast<const bf16x8*>(&Bs[(wn + i * 16 + l16) * 32 + quad * 8]);
    }
#pragma unroll
    for (int i = 0; i < 4; ++i)
#pragma unroll
      for (int j = 0; j < 4; ++j) acc[i][j] = MFMA16(af[i], bfr[j], acc[i][j]);
  }
#pragma unroll
  for (int i = 0; i < 4; ++i)
#pragma unroll
    for (int j = 0; j < 4; ++j)
#pragma unroll
      for (int r = 0; r < 4; ++r) {
        int row = tm + wm + i * 16 + quad * 4 + r;
        int col = tn + wn + j * 16 + l16;
        storeC(&C[(size_t)row * N + col], acc[i][j][r]);
      }
}

// ---------------- K/V fragment packing --------------------------------------
// Kp: per (bk, kt64) an 8192-elem block; tile (c,nt) holds lane-linear
//     B-fragments: elem(lane=quad*16+l16, j) = K[key=kt+l16*4+nt][c*32+quad*8+j]
// Vp: per (bk, kt32) a 4096-elem block; tile dt: elem(lane,j) =
//     V[key=kt+quad*8+j][dim=dt*16+l16]
__global__ __launch_bounds__(256) void kvpack(const unsigned short* __restrict__ QKV,
                                              unsigned short* __restrict__ Kp,
                                              unsigned short* __restrict__ Vp) {
  const int tid  = threadIdx.x;
  const int kt64 = blockIdx.x;           // 0..31
  const int bk   = blockIdx.y;           // b*4 + kvh
  const int b = bk >> 2, kvh = bk & 3;
  const int kt = kt64 * 64;
  const int bT = b * T_SEQ;
  const int dq = tid & 15;               // dim octet: dims dq*8..dq*8+7

  unsigned short* kdst = &Kp[(size_t)(bk * 32 + kt64) * 8192];
#pragma unroll
  for (int it = 0; it < 4; ++it) {
    int key = it * 16 + (tid >> 4);
    float4 v = *reinterpret_cast<const float4*>(
        &QKV[(size_t)(bT + kt + key) * QKVN + 2048 + kvh * HS + dq * 8]);
    int c = dq >> 2, quad = dq & 3, nt = key & 3, l16s = key >> 2;
    *reinterpret_cast<float4*>(
        &kdst[((size_t)((c * 4 + nt) * 64 + quad * 16 + l16s)) * 8]) = v;
  }

#pragma unroll
  for (int it = 0; it < 4; ++it) {
    int key = it * 16 + (tid >> 4);
    float4 v = *reinterpret_cast<const float4*>(
        &QKV[(size_t)(bT + kt + key) * QKVN + 2560 + kvh * HS + dq * 8]);
    const unsigned short* pv = reinterpret_cast<const unsigned short*>(&v);
    int kt32 = kt64 * 2 + (key >> 5);
    int quad = (key & 31) >> 3, j = key & 7;
    unsigned short* vdst = &Vp[(size_t)(bk * 64 + kt32) * 4096];
#pragma unroll
    for (int j2 = 0; j2 < 8; ++j2) {
      int d = dq * 8 + j2, dt = d >> 4, l16v = d & 15;
      vdst[((size_t)(dt * 64 + quad * 16 + l16v)) * 8 + j] = pv[j2];
    }
  }
}

// ---------------- flash attention, k-split across waves ---------------------
// grid (T/32, NH, B); block 256 = 4 waves, ALL on the same (32q, head);
// wave w takes chunks w, w+4, w+8, ... (O,l linear in chunks -> plain-add
// reduction). 2-stage LDS tree reduce + coalesced Y store via LDS staging.
__global__ __launch_bounds__(256) void attn_kernel(const unsigned short* __restrict__ QKV,
                                                   const unsigned short* __restrict__ Kp,
                                                   const unsigned short* __restrict__ Vp,
                                                   unsigned short* __restrict__ Y) {
  __shared__ __align__(16) char smem[2 * 64 * RSTR * 4];   // 38912 B
  unsigned short* Ps  = reinterpret_cast<unsigned short*>(smem);
  float*          Red = reinterpret_cast<float*>(smem);
  unsigned short* Yst = reinterpret_cast<unsigned short*>(smem);

  const int tid  = threadIdx.x;
  const int wave = tid >> 6, lane = tid & 63;
  const int quad = lane >> 4, l16 = lane & 15;
  const int qt0 = (int)(gridDim.x - 1 - blockIdx.x) * 32;  // long blocks first
  const int h   = blockIdx.y, b = blockIdx.z;
  const int kvh = h >> 2;
  const int bk  = b * NKV + kvh;
  const int bT  = b * T_SEQ;
  unsigned short* Pw = &Ps[wave * 32 * PSTR];

  // Q fragments (A-operand: m=l16, k=quad*8+j); Q pre-scaled by log2e/sqrt(HS)
  bf16x8 qa[2][4];
#pragma unroll
  for (int mt = 0; mt < 2; ++mt)
#pragma unroll
    for (int c = 0; c < 4; ++c)
      qa[mt][c] = *reinterpret_cast<const bf16x8*>(
          &QKV[(size_t)(bT + qt0 + mt * 16 + l16) * QKVN + h * HS + c * 32 + quad * 8]);

  bf16x8 ones;
#pragma unroll
  for (int j = 0; j < 8; ++j) ones[j] = us2b(0x3F80);  // bf16 1.0

  f32x4 o[2][9];   // [mt][dt]; dt=8 accumulates row-sum l
#pragma unroll
  for (int mt = 0; mt < 2; ++mt)
#pragma unroll
    for (int dt = 0; dt < 9; ++dt) o[mt][dt] = fzero4();

  const int start = (qt0 >= 1024) ? ((qt0 - 1023) & ~63) : 0;
  const int sink  = (start > 0) ? 1 : 0;
  const int nch   = ((qt0 + 32 - start + 63) >> 6) + sink;

  for (int ci = wave; ci < nch; ci += 4) {
    const bool is_sink = (sink && ci == 0);
    const int  kt  = is_sink ? 0 : start + (ci - sink) * 64;
    const int  rem = qt0 + 32 - kt;
    const int  kcmax = is_sink ? 1 : (rem >= 64 ? 2 : ((rem + 31) >> 5));
    const bool full  = !is_sink && (kt + 63 <= qt0) && (kt >= qt0 - 992);

    f32x4 s[2][4];
#pragma unroll
    for (int nt = 0; nt < 4; ++nt) { s[0][nt] = fzero4(); s[1][nt] = fzero4(); }

    if (is_sink) {
      // direct (uncoalesced) K loads; 16 rows, once per block
#pragma unroll
      for (int c = 0; c < 4; ++c) {
        bf16x8 kf = *reinterpret_cast<const bf16x8*>(
            &QKV[(size_t)(bT + l16) * QKVN + 2048 + kvh * HS + c * 32 + quad * 8]);
        s[0][0] = MFMA16(qa[0][c], kf, s[0][0]);
        s[1][0] = MFMA16(qa[1][c], kf, s[1][0]);
      }
#pragma unroll
      for (int mt = 0; mt < 2; ++mt)
#pragma unroll
        for (int r = 0; r < 4; ++r) {
          const int row = mt * 16 + quad * 4 + r;
          Pw[row * PSTR + l16]      = (l16 < SINKN) ? f2bu(EXP2(s[mt][0][r])) : 0;
          Pw[row * PSTR + 16 + l16] = 0;
        }
      asm volatile("s_waitcnt lgkmcnt(0)" ::: "memory");
      const unsigned short* vb = &Vp[(size_t)(bk * 64) * 4096 + lane * 8];
#pragma unroll
      for (int mt = 0; mt < 2; ++mt) {
        bf16x8 pf = *reinterpret_cast<const bf16x8*>(
            &Pw[(mt * 16 + l16) * PSTR + quad * 8]);
#pragma unroll
        for (int dt = 0; dt < 8; ++dt) {
          bf16x8 vf = *reinterpret_cast<const bf16x8*>(&vb[dt * 512]);
          o[mt][dt] = MFMA16(pf, vf, o[mt][dt]);
        }
        o[mt][8] = MFMA16(pf, ones, o[mt][8]);
      }
      continue;
    }

    const unsigned short* kb = &Kp[(size_t)(bk * 32 + (kt >> 6)) * 8192 + lane * 8];
    const unsigned short* vb = &Vp[(size_t)(bk * 64 + (kt >> 5)) * 4096 + lane * 8];

    // QK^T: tile (c,nt) at byte offset ((c*4+nt)*1024); group by c so each
    // group's 4 loads use imm13 offsets off one base pointer.
#pragma unroll
    for (int c = 0; c < 4; ++c) {
      const unsigned short* kbg = kb + c * 2048;
      bf16x8 kf[4];
#pragma unroll
      for (int nt = 0; nt < 4; ++nt)
        kf[nt] = *reinterpret_cast<const bf16x8*>(&kbg[nt * 512]);
#pragma unroll
      for (int nt = 0; nt < 4; ++nt) {
        s[0][nt] = MFMA16(qa[0][c], kf[nt], s[0][nt]);
        s[1][nt] = MFMA16(qa[1][c], kf[nt], s[1][nt]);
      }
    }

    if (full) {
#pragma unroll
      for (int mt = 0; mt < 2; ++mt)
#pragma unroll
        for (int r = 0; r < 4; ++r) {
          const int row = mt * 16 + quad * 4 + r;
          uint2 pk;
          pk.x = pkhi(EXP2(s[mt][0][r]), EXP2(s[mt][1][r]));
          pk.y = pkhi(EXP2(s[mt][2][r]), EXP2(s[mt][3][r]));
          *reinterpret_cast<uint2*>(&Pw[row * PSTR + l16 * 4]) = pk;
        }
    } else {
#pragma unroll
      for (int mt = 0; mt < 2; ++mt)
#pragma unroll
        for (int r = 0; r < 4; ++r) {
          const int row = mt * 16 + quad * 4 + r;
          const int qi  = qt0 + row;
          float p[4];
#pragma unroll
          for (int nt = 0; nt < 4; ++nt) {
            int kj = kt + l16 * 4 + nt;
            bool ok = ((kj <= qi) && (kj + (WIN - 1) >= qi)) ||
                      ((kj < SINKN) && (qi >= SINKN));
            p[nt] = ok ? EXP2(s[mt][nt][r]) : 0.f;
          }
          uint2 pk;
          pk.x = pkhi(p[0], p[1]);
          pk.y = pkhi(p[2], p[3]);
          *reinterpret_cast<uint2*>(&Pw[row * PSTR + l16 * 4]) = pk;
        }
    }
    asm volatile("s_waitcnt lgkmcnt(0)" ::: "memory");  // wave-local P drain

#pragma unroll
    for (int kc = 0; kc < 2; ++kc)
      if (kc < kcmax) {
        const unsigned short* vbk  = vb + kc * 4096;
#pragma unroll
        for (int mt = 0; mt < 2; ++mt) {
          bf16x8 pf = *reinterpret_cast<const bf16x8*>(
              &Pw[(mt * 16 + l16) * PSTR + kc * 32 + quad * 8]);
#pragma unroll
          for (int dt = 0; dt < 8; ++dt) {
            bf16x8 vf = *reinterpret_cast<const bf16x8*>(
                &vbk[(dt & 3) * 512 + (dt >> 2) * 2048]);
            o[mt][dt] = MFMA16(pf, vf, o[mt][dt]);
          }
          o[mt][8] = MFMA16(pf, ones, o[mt][8]);
        }
      }
  }

  // ---- cross-wave reduction (O,l additive) ----
  __syncthreads();                                   // all chunk loops done
  if (wave >= 2) {                                   // waves 2,3 -> regions 0,1
    float* slot = &Red[((wave - 2) * 64 + lane) * RSTR];
#pragma unroll
    for (int mt = 0; mt < 2; ++mt)
#pragma unroll
      for (int dt = 0; dt < 9; ++dt)
        *reinterpret_cast<f32x4*>(slot + (mt * 9 + dt) * 4) = o[mt][dt];
  }
  __syncthreads();
  if (wave < 2) {                                    // waves 0,1 add regions 0,1
    float* slot = &Red[(wave * 64 + lane) * RSTR];
#pragma unroll
    for (int mt = 0; mt < 2; ++mt)
#pragma unroll
      for (int dt = 0; dt < 9; ++dt)
        o[mt][dt] += *reinterpret_cast<f32x4*>(slot + (mt * 9 + dt) * 4);
    if (wave == 1) {                                 // wave1 rewrites region 1
      float* s1 = &Red[(64 + lane) * RSTR];
#pragma unroll
      for (int mt = 0; mt < 2; ++mt)
#pragma unroll
        for (int dt = 0; dt < 9; ++dt)
          *reinterpret_cast<f32x4*>(s1 + (mt * 9 + dt) * 4) = o[mt][dt];
    }
  }
  __syncthreads();
  if (wave == 0) {
    float* s1 = &Red[(64 + lane) * RSTR];
#pragma unroll
    for (int mt = 0; mt < 2; ++mt) {
#pragma unroll
      for (int dt = 0; dt < 9; ++dt)
        o[mt][dt] += *reinterpret_cast<f32x4*>(s1 + (mt * 9 + dt) * 4);
      float inv[4];
#pragma unroll
      for (int r = 0; r < 4; ++r) inv[r] = __builtin_amdgcn_rcpf(o[mt][8][r]);
#pragma unroll
      for (int dt = 0; dt < 8; ++dt)
#pragma unroll
        for (int r = 0; r < 4; ++r)
          Yst[(mt * 16 + quad * 4 + r) * 136 + dt * 16 + l16] =
              f2bu(o[mt][dt][r] * inv[r]);
    }
  }
  __syncthreads();
  // coalesced Y store: 32 rows x 128 cols bf16, 256 threads x 2 b128
#pragma unroll
  for (int it = 0; it < 2; ++it) {
    int row = it * 16 + (tid >> 4);
    int col = (tid & 15) * 8;
    *reinterpret_cast<uint4*>(&Y[(size_t)(bT + qt0 + row) * CDIM + h * HS + col]) =
        *reinterpret_cast<const uint4*>(&Yst[row * 136 + col]);
  }
}

// ---------------------------------------------------------------------------
extern "C" void kernel_launch(void* const* d_in, const int* in_sizes, int n_in,
                              void* d_out, int out_size, void* d_ws, size_t ws_size,
                              hipStream_t stream) {
  const float* x  = (const float*)d_in[0];
  const float* Wq = (const float*)d_in[1];
  const float* Wk = (const float*)d_in[2];
  const float* Wv = (const float*)d_in[3];
  const float* Wo = (const float*)d_in[4];
  float* out = (float*)d_out;

  // workspace layout (bf16 elems); total 62.9 MB
  unsigned short* base = (unsigned short*)d_ws;
  unsigned short* xb   = base;              // x bf16 (8388608); later Y
  unsigned short* wqb  = xb + OFF_WQ;       // Wq bf16; later Kp+Vp
  unsigned short* wob  = xb + OFF_WO;       // Wo bf16
  unsigned short* QKVb = xb + SZ_ALL;       // QKV (4096 x 3072)
  unsigned short* Kpb  = wqb;               // packed K (2097152)
  unsigned short* Vpb  = wqb + 2097152;     // packed V (2097152)
  unsigned short* Yb   = xb;                // attn out (4096 x 2048)

  // 1/sqrt(HS) * log2(e) folded into Wq so exp2 is native
  const float qscale = 0.08838834764831845f * 1.4426950408889634f;
  f2b_all<<<SZ_ALL / 1024, 256, 0, stream>>>(x, Wq, Wk, Wv, Wo, xb, qscale);

  // fused QKV projection: B = [Wq; Wk; Wv], N = 3072
  gemm_abt<unsigned short><<<dim3(32, 24), 256, 0, stream>>>(xb, wqb, QKVb, 4096, QKVN, 2048);

  kvpack<<<dim3(32, 8), 256, 0, stream>>>(QKVb, Kpb, Vpb);

  attn_kernel<<<dim3(64, 16, 2), 256, 0, stream>>>(QKVb, Kpb, Vpb, Yb);

  gemm_abt<float><<<dim3(32, 16), 256, 0, stream>>>(Yb, wob, out, 4096, 2048, 2048);
}

// Round 7
// 299.907 us; speedup vs baseline: 1.7039x; 1.2468x over previous
//
#include <hip/hip_runtime.h>

// ---------------------------------------------------------------------------
// GQA block: out = Attn(x@Wq^T, x@Wk^T, x@Wv^T; sliding-window+sink) @ Wo^T
// B=2 T=2048 C=2048, NH=16 NKV=4 HS=128, WINDOW=1024 SINK=4.
// R7: attention K/V staged into shared LDS via async global_load_lds (one
// vmcnt drain per chunk instead of ~48 serialized global-load latencies --
// R5/R6's 19k-cycle chunks). Block = 4 waves = 4 heads of one KV group, all
// sharing the same chunk sequence; K/V pre-packed in MFMA fragment order so
// staging is a flat copy and LDS reads are conflict-free b128. Barrier-free
// softmax per wave (bounded scores, no online max; l via ones-column MFMA).
// ---------------------------------------------------------------------------

#define T_SEQ 2048
#define NKV   4
#define HS    128
#define CDIM  2048
#define QKVN  3072
#define WIN   1024
#define SINKN 4
#define PSTR  68        // P LDS row stride (elems)

typedef __bf16 bf16x8 __attribute__((ext_vector_type(8)));
typedef float  f32x4  __attribute__((ext_vector_type(4)));

#define MFMA16(A, B, C) __builtin_amdgcn_mfma_f32_16x16x32_bf16(A, B, C, 0, 0, 0)
#define EXP2(x) __builtin_amdgcn_exp2f(x)

__device__ inline unsigned short f2bu(float f) {  // fp32 -> bf16 bits, RNE
  unsigned int u = __float_as_uint(f);
  u += 0x7fffu + ((u >> 16) & 1u);
  return (unsigned short)(u >> 16);
}
// pack hi16(f0), hi16(f1) -> one u32 (bf16 truncation; bias cancels in O/l)
__device__ inline unsigned int pkhi(float f0, float f1) {
  return __builtin_amdgcn_perm(__float_as_uint(f1), __float_as_uint(f0),
                               0x07060302u);
}
__device__ inline __bf16 us2b(unsigned short u) {
  union { unsigned short u; __bf16 b; } t; t.u = u; return t.b;
}
__device__ inline f32x4 fzero4() { f32x4 z = {0.f, 0.f, 0.f, 0.f}; return z; }

// async global->LDS, 16B/lane. LDS dest is wave-uniform base + lane*16 (m104).
__device__ __forceinline__ void glds16(const void* g, const void* lds_uniform) {
  typedef __attribute__((address_space(1))) void gv;
  typedef __attribute__((address_space(3))) void lv;
  __builtin_amdgcn_global_load_lds((gv*)(unsigned long long)g,
                                   (lv*)(unsigned int)(unsigned long long)lds_uniform,
                                   16, 0, 0);
}

// ---------------- fused fp32 -> bf16 conversion (all 5 inputs) --------------
#define SZ_X  8388608
#define SZ_WQ 4194304
#define SZ_WK 1048576
#define OFF_WQ (SZ_X)
#define OFF_WK (SZ_X + SZ_WQ)
#define OFF_WV (OFF_WK + SZ_WK)
#define OFF_WO (OFF_WV + SZ_WK)
#define SZ_ALL (OFF_WO + SZ_WQ)

__global__ __launch_bounds__(256) void f2b_all(const float* __restrict__ x,
                                               const float* __restrict__ wq,
                                               const float* __restrict__ wk,
                                               const float* __restrict__ wv,
                                               const float* __restrict__ wo,
                                               unsigned short* __restrict__ out,
                                               float qs) {
  int i = (blockIdx.x * 256 + threadIdx.x) * 4;
  const float* src; int off; float sc = 1.0f;
  if (i < OFF_WQ)      { src = x;  off = 0; }
  else if (i < OFF_WK) { src = wq; off = OFF_WQ; sc = qs; }
  else if (i < OFF_WV) { src = wk; off = OFF_WK; }
  else if (i < OFF_WO) { src = wv; off = OFF_WV; }
  else                 { src = wo; off = OFF_WO; }
  float4 v = *reinterpret_cast<const float4*>(src + (i - off));
  ushort4 o;
  o.x = f2bu(v.x * sc); o.y = f2bu(v.y * sc);
  o.z = f2bu(v.z * sc); o.w = f2bu(v.w * sc);
  *reinterpret_cast<ushort4*>(out + i) = o;
}

// ---------------- C = A (M,K) @ B^T (N,K), m97 structure --------------------
__device__ inline void storeC(unsigned short* p, float v) { *p = f2bu(v); }
__device__ inline void storeC(float* p, float v) { *p = v; }

template <typename OutT>
__global__ __launch_bounds__(256) void gemm_abt(const unsigned short* __restrict__ A,
                                                const unsigned short* __restrict__ B,
                                                OutT* __restrict__ C,
                                                int M, int N, int K) {
  __shared__ __align__(16) unsigned short As[128 * 32];
  __shared__ __align__(16) unsigned short Bs[128 * 32];
  const int tid  = threadIdx.x;
  const int wave = tid >> 6, lane = tid & 63;
  const int quad = lane >> 4, l16 = lane & 15;
  const int wm = (wave >> 1) * 64, wn = (wave & 1) * 64;
  const int tm = blockIdx.x * 128, tn = blockIdx.y * 128;

  f32x4 acc[4][4];
#pragma unroll
  for (int i = 0; i < 4; ++i)
#pragma unroll
    for (int j = 0; j < 4; ++j) acc[i][j] = fzero4();

  for (int k0 = 0; k0 < K; k0 += 32) {
    __syncthreads();
#pragma unroll
    for (int it = 0; it < 2; ++it) {
      int chunk = wave * 2 + it;             // 0..7, wave-uniform
      int f = (chunk * 64 + lane) * 8;       // elem idx in 128x32 tile
      int r = f >> 5, c = f & 31;
      glds16(&A[(size_t)(tm + r) * K + k0 + c], &As[chunk * 512]);
      glds16(&B[(size_t)(tn + r) * K + k0 + c], &Bs[chunk * 512]);
    }
    __syncthreads();
    bf16x8 af[4], bfr[4];
#pragma unroll
    for (int i = 0; i < 4; ++i) {
      af[i]  = *reinterpret_cast<const bf16x8*>(&As[(wm + i * 16 + l16) * 32 + quad * 8]);
      bfr[i] = *reinterpret_cast<const bf16x8*>(&Bs[(wn + i * 16 + l16) * 32 + quad * 8]);
    }
#pragma unroll
    for (int i = 0; i < 4; ++i)
#pragma unroll
      for (int j = 0; j < 4; ++j) acc[i][j] = MFMA16(af[i], bfr[j], acc[i][j]);
  }
#pragma unroll
  for (int i = 0; i < 4; ++i)
#pragma unroll
    for (int j = 0; j < 4; ++j)
#pragma unroll
      for (int r = 0; r < 4; ++r) {
        int row = tm + wm + i * 16 + quad * 4 + r;
        int col = tn + wn + j * 16 + l16;
        storeC(&C[(size_t)row * N + col], acc[i][j][r]);
      }
}

// ---------------- K/V fragment packing --------------------------------------
// Kp: per (bk, kt64) an 8192-elem block; tile (c,nt) holds lane-linear
//     B-fragments: elem(lane=quad*16+l16, j) = K[key=kt+l16*4+nt][c*32+quad*8+j]
// Vp: per (bk, kt32) a 4096-elem block; tile dt: elem(lane,j) =
//     V[key=kt+quad*8+j][dim=dt*16+l16]
__global__ __launch_bounds__(256) void kvpack(const unsigned short* __restrict__ QKV,
                                              unsigned short* __restrict__ Kp,
                                              unsigned short* __restrict__ Vp) {
  const int tid  = threadIdx.x;
  const int kt64 = blockIdx.x;           // 0..31
  const int bk   = blockIdx.y;           // b*4 + kvh
  const int b = bk >> 2, kvh = bk & 3;
  const int kt = kt64 * 64;
  const int bT = b * T_SEQ;
  const int dq = tid & 15;               // dim octet: dims dq*8..dq*8+7

  unsigned short* kdst = &Kp[(size_t)(bk * 32 + kt64) * 8192];
#pragma unroll
  for (int it = 0; it < 4; ++it) {
    int key = it * 16 + (tid >> 4);
    float4 v = *reinterpret_cast<const float4*>(
        &QKV[(size_t)(bT + kt + key) * QKVN + 2048 + kvh * HS + dq * 8]);
    int c = dq >> 2, quad = dq & 3, nt = key & 3, l16s = key >> 2;
    *reinterpret_cast<float4*>(
        &kdst[((size_t)((c * 4 + nt) * 64 + quad * 16 + l16s)) * 8]) = v;
  }

#pragma unroll
  for (int it = 0; it < 4; ++it) {
    int key = it * 16 + (tid >> 4);
    float4 v = *reinterpret_cast<const float4*>(
        &QKV[(size_t)(bT + kt + key) * QKVN + 2560 + kvh * HS + dq * 8]);
    const unsigned short* pv = reinterpret_cast<const unsigned short*>(&v);
    int kt32 = kt64 * 2 + (key >> 5);
    int quad = (key & 31) >> 3, j = key & 7;
    unsigned short* vdst = &Vp[(size_t)(bk * 64 + kt32) * 4096];
#pragma unroll
    for (int j2 = 0; j2 < 8; ++j2) {
      int d = dq * 8 + j2, dt = d >> 4, l16v = d & 15;
      vdst[((size_t)(dt * 64 + quad * 16 + l16v)) * 8 + j] = pv[j2];
    }
  }
}

// ---------------- flash attention, shared async-LDS K/V ---------------------
// grid (T/32, NKV, B); block 256 = 4 waves = heads kvh*4..kvh*4+3, all on the
// same 32 queries -> identical chunk sequence. Per chunk: glds16-stage K+V
// tiles (flat copy of packed layout), one barrier, MFMA ops from LDS.
__global__ __launch_bounds__(256) void attn_kernel(const unsigned short* __restrict__ QKV,
                                                   const unsigned short* __restrict__ Kp,
                                                   const unsigned short* __restrict__ Vp,
                                                   unsigned short* __restrict__ Y) {
  __shared__ __align__(16) unsigned short KVs[16384];   // Ks[8192] | Vs[8192]
  __shared__ __align__(16) unsigned short Ps[4 * 32 * PSTR];
  unsigned short* Ks = KVs;
  unsigned short* Vs = KVs + 8192;

  const int tid  = threadIdx.x;
  const int wave = tid >> 6, lane = tid & 63;
  const int quad = lane >> 4, l16 = lane & 15;
  const int qt0 = (int)(gridDim.x - 1 - blockIdx.x) * 32;  // long blocks first
  const int kvh = blockIdx.y, b = blockIdx.z;
  const int h   = kvh * 4 + wave;
  const int bk  = b * NKV + kvh;
  const int bT  = b * T_SEQ;
  unsigned short* Pw = &Ps[wave * 32 * PSTR];

  // Q fragments (A-operand: m=l16, k=quad*8+j); Q pre-scaled by log2e/sqrt(HS)
  bf16x8 qa[2][4];
#pragma unroll
  for (int mt = 0; mt < 2; ++mt)
#pragma unroll
    for (int c = 0; c < 4; ++c)
      qa[mt][c] = *reinterpret_cast<const bf16x8*>(
          &QKV[(size_t)(bT + qt0 + mt * 16 + l16) * QKVN + h * HS + c * 32 + quad * 8]);

  bf16x8 ones;
#pragma unroll
  for (int j = 0; j < 8; ++j) ones[j] = us2b(0x3F80);  // bf16 1.0

  f32x4 o[2][9];   // [mt][dt]; dt=8 accumulates row-sum l
#pragma unroll
  for (int mt = 0; mt < 2; ++mt)
#pragma unroll
    for (int dt = 0; dt < 9; ++dt) o[mt][dt] = fzero4();

  const int start = (qt0 >= 1024) ? ((qt0 - 1023) & ~63) : 0;
  const int sink  = (start > 0) ? 1 : 0;
  const int nch   = ((qt0 + 32 - start + 63) >> 6) + sink;

  for (int ci = 0; ci < nch; ++ci) {
    const bool is_sink = (sink && ci == 0);
    const int  kt  = is_sink ? 0 : start + (ci - sink) * 64;
    const int  rem = qt0 + 32 - kt;
    const int  kcmax = is_sink ? 1 : (rem >= 64 ? 2 : ((rem + 31) >> 5));
    const bool full  = !is_sink && (kt + 63 <= qt0) && (kt >= qt0 - 992);

    __syncthreads();   // previous chunk's LDS reads complete
    {
      const unsigned short* kg = &Kp[(size_t)(bk * 32 + (kt >> 6)) * 8192 + lane * 8];
      const unsigned short* vg = &Vp[(size_t)(bk * 64 + (kt >> 5)) * 4096 + lane * 8];
#pragma unroll
      for (int i = 0; i < 4; ++i) {
        int part = wave * 4 + i;                    // wave-uniform
        glds16(kg + part * 512, &Ks[part * 512]);
        glds16(vg + part * 512, &Vs[part * 512]);
      }
    }
    __syncthreads();   // implies vmcnt(0) drain of the staging loads

    // ---- S = Q K^T from LDS (conflict-free b128 reads) ----
    f32x4 s[2][4];
#pragma unroll
    for (int nt = 0; nt < 4; ++nt) { s[0][nt] = fzero4(); s[1][nt] = fzero4(); }
#pragma unroll
    for (int c = 0; c < 4; ++c) {
#pragma unroll
      for (int nt = 0; nt < 4; ++nt) {
        bf16x8 kf = *reinterpret_cast<const bf16x8*>(&Ks[(c * 4 + nt) * 512 + lane * 8]);
        s[0][nt] = MFMA16(qa[0][c], kf, s[0][nt]);
        s[1][nt] = MFMA16(qa[1][c], kf, s[1][nt]);
      }
    }

    // ---- P = exp2(S) with mask (key of col: kt + l16*4 + nt) ----
    if (full) {
#pragma unroll
      for (int mt = 0; mt < 2; ++mt)
#pragma unroll
        for (int r = 0; r < 4; ++r) {
          const int row = mt * 16 + quad * 4 + r;
          uint2 pk;
          pk.x = pkhi(EXP2(s[mt][0][r]), EXP2(s[mt][1][r]));
          pk.y = pkhi(EXP2(s[mt][2][r]), EXP2(s[mt][3][r]));
          *reinterpret_cast<uint2*>(&Pw[row * PSTR + l16 * 4]) = pk;
        }
    } else {
#pragma unroll
      for (int mt = 0; mt < 2; ++mt)
#pragma unroll
        for (int r = 0; r < 4; ++r) {
          const int row = mt * 16 + quad * 4 + r;
          const int qi  = qt0 + row;
          float p[4];
#pragma unroll
          for (int nt = 0; nt < 4; ++nt) {
            int kj = kt + l16 * 4 + nt;
            bool ok = ((kj <= qi) && (kj + (WIN - 1) >= qi)) ||
                      ((kj < SINKN) && (qi >= SINKN));
            p[nt] = ok ? EXP2(s[mt][nt][r]) : 0.f;
          }
          uint2 pk;
          pk.x = pkhi(p[0], p[1]);
          pk.y = pkhi(p[2], p[3]);
          *reinterpret_cast<uint2*>(&Pw[row * PSTR + l16 * 4]) = pk;
        }
    }
    asm volatile("s_waitcnt lgkmcnt(0)" ::: "memory");  // wave-local P drain

    // ---- O += P V (+ ones column for l), V from LDS ----
#pragma unroll
    for (int kc = 0; kc < 2; ++kc)
      if (kc < kcmax) {
#pragma unroll
        for (int mt = 0; mt < 2; ++mt) {
          bf16x8 pf = *reinterpret_cast<const bf16x8*>(
              &Pw[(mt * 16 + l16) * PSTR + kc * 32 + quad * 8]);
#pragma unroll
          for (int dt = 0; dt < 8; ++dt) {
            bf16x8 vf = *reinterpret_cast<const bf16x8*>(
                &Vs[kc * 4096 + dt * 512 + lane * 8]);
            o[mt][dt] = MFMA16(pf, vf, o[mt][dt]);
          }
          o[mt][8] = MFMA16(pf, ones, o[mt][8]);
        }
      }
  }

  // ---- normalize, stage in LDS (reuse KVs), coalesced Y store ----
  __syncthreads();                       // all waves done with KVs
  unsigned short* Yst = KVs;             // 32 rows x 512 cols (heads kvh*4..+3)
#pragma unroll
  for (int mt = 0; mt < 2; ++mt) {
    float inv[4];
#pragma unroll
    for (int r = 0; r < 4; ++r) inv[r] = __builtin_amdgcn_rcpf(o[mt][8][r]);
#pragma unroll
    for (int dt = 0; dt < 8; ++dt)
#pragma unroll
      for (int r = 0; r < 4; ++r)
        Yst[(mt * 16 + quad * 4 + r) * 512 + wave * 128 + dt * 16 + l16] =
            f2bu(o[mt][dt][r] * inv[r]);
  }
  __syncthreads();
#pragma unroll
  for (int it = 0; it < 8; ++it) {
    int idx = it * 256 + tid;
    int row = idx >> 6, col = (idx & 63) * 8;
    *reinterpret_cast<uint4*>(
        &Y[(size_t)(bT + qt0 + row) * CDIM + kvh * 512 + col]) =
        *reinterpret_cast<const uint4*>(&Yst[row * 512 + col]);
  }
}

// ---------------------------------------------------------------------------
extern "C" void kernel_launch(void* const* d_in, const int* in_sizes, int n_in,
                              void* d_out, int out_size, void* d_ws, size_t ws_size,
                              hipStream_t stream) {
  const float* x  = (const float*)d_in[0];
  const float* Wq = (const float*)d_in[1];
  const float* Wk = (const float*)d_in[2];
  const float* Wv = (const float*)d_in[3];
  const float* Wo = (const float*)d_in[4];
  float* out = (float*)d_out;

  // workspace layout (bf16 elems); total 62.9 MB
  unsigned short* base = (unsigned short*)d_ws;
  unsigned short* xb   = base;              // x bf16 (8388608); later Y
  unsigned short* wqb  = xb + OFF_WQ;       // Wq bf16; later Kp+Vp
  unsigned short* wob  = xb + OFF_WO;       // Wo bf16
  unsigned short* QKVb = xb + SZ_ALL;       // QKV (4096 x 3072)
  unsigned short* Kpb  = wqb;               // packed K (2097152)
  unsigned short* Vpb  = wqb + 2097152;     // packed V (2097152)
  unsigned short* Yb   = xb;                // attn out (4096 x 2048)

  // 1/sqrt(HS) * log2(e) folded into Wq so exp2 is native
  const float qscale = 0.08838834764831845f * 1.4426950408889634f;
  f2b_all<<<SZ_ALL / 1024, 256, 0, stream>>>(x, Wq, Wk, Wv, Wo, xb, qscale);

  // fused QKV projection: B = [Wq; Wk; Wv], N = 3072
  gemm_abt<unsigned short><<<dim3(32, 24), 256, 0, stream>>>(xb, wqb, QKVb, 4096, QKVN, 2048);

  kvpack<<<dim3(32, 8), 256, 0, stream>>>(QKVb, Kpb, Vpb);

  attn_kernel<<<dim3(64, 4, 2), 256, 0, stream>>>(QKVb, Kpb, Vpb, Yb);

  gemm_abt<float><<<dim3(32, 16), 256, 0, stream>>>(Yb, wob, out, 4096, 2048, 2048);
}